// Round 7
// baseline (496.992 us; speedup 1.0000x reference)
//
#include <hip/hip_runtime.h>
#include <math.h>

namespace {

constexpr int B_ = 4;
constexpr int C_ = 256;
constexpr int C4_ = 64;
constexpr int N_ = 4096;

typedef __attribute__((ext_vector_type(8))) short bf16x8;
typedef __attribute__((ext_vector_type(4))) float f32x4;

__device__ __forceinline__ unsigned short bf16_rne(float f) {
    unsigned u = __float_as_uint(f);
    u += 0x7fffu + ((u >> 16) & 1u);
    return (unsigned short)(u >> 16);
}

// XCD-aware swizzle: batch b owns 2 XCDs (round-robin dispatch assumption).
__device__ __forceinline__ void swizzle(int L, int& b, int& nt) {
    b = (L & 7) >> 1;
    nt = (L >> 3) * 2 + (L & 1);
}

// Convert wq||wv -> wcomb bf16 [320,256], wt -> wtb bf16 [256,256].
__global__ __launch_bounds__(256) void cvt_kernel(
        const float* __restrict__ wq, const float* __restrict__ wv,
        const float* __restrict__ wt, unsigned short* __restrict__ wcomb,
        unsigned short* __restrict__ wtb) {
    const int i = (blockIdx.x * 256 + threadIdx.x) * 4;
    const float* src;
    unsigned short* dst;
    if (i < 16384) { src = wq + i; dst = wcomb + i; }
    else if (i < 81920) { src = wv + (i - 16384); dst = wcomb + i; }
    else { src = wt + (i - 81920); dst = wtb + (i - 81920); }
    const float4 f = *reinterpret_cast<const float4*>(src);
    ushort4 u;
    u.x = bf16_rne(f.x); u.y = bf16_rne(f.y);
    u.z = bf16_rne(f.z); u.w = bf16_rne(f.w);
    *reinterpret_cast<ushort4*>(dst) = u;
}

// MFMA projection: one 1024-thread block per 64-n tile; 16 waves = 4 n-strips
// x 4 o-quarters (5 ot each). x staged once per block.
__global__ __launch_bounds__(1024, 4) void proj_kernel(
        const float* __restrict__ x, const unsigned short* __restrict__ wcomb,
        const float* __restrict__ bv, unsigned short* __restrict__ qkT,
        unsigned short* __restrict__ v) {
    __shared__ unsigned short xs[2][64][40];
    int b, nt;
    swizzle(blockIdx.x, b, nt);
    const int n0 = nt * 64;
    const int tid = threadIdx.x;
    const int wave = tid >> 6, lane = tid & 63;
    const int ws = wave & 3, oq = wave >> 2;
    const int quad = lane >> 4, l15 = lane & 15;
    const int ca = tid >> 6, na = tid & 63;
    const int cb = (tid + 1024) >> 6, nb2 = (tid + 1024) & 63;
    f32x4 acc[5];
#pragma unroll
    for (int ot = 0; ot < 5; ++ot) acc[ot] = (f32x4){0.f, 0.f, 0.f, 0.f};
    xs[0][na][ca] = bf16_rne(x[((size_t)b * C_ + ca) * N_ + n0 + na]);
    xs[0][nb2][cb] = bf16_rne(x[((size_t)b * C_ + cb) * N_ + n0 + nb2]);
    __syncthreads();
    for (int ch = 0; ch < 8; ++ch) {
        const int buf = ch & 1;
        float la = 0.f, lb = 0.f;
        if (ch < 7) {
            la = x[((size_t)b * C_ + (ch + 1) * 32 + ca) * N_ + n0 + na];
            lb = x[((size_t)b * C_ + (ch + 1) * 32 + cb) * N_ + n0 + nb2];
        }
        const bf16x8 a = *reinterpret_cast<const bf16x8*>(&xs[buf][ws * 16 + l15][quad * 8]);
#pragma unroll
        for (int ot = 0; ot < 5; ++ot) {
            const int gro = oq * 5 + ot;
            const bf16x8 wb = *reinterpret_cast<const bf16x8*>(
                wcomb + (size_t)(gro * 16 + l15) * C_ + ch * 32 + quad * 8);
            acc[ot] = __builtin_amdgcn_mfma_f32_16x16x32_bf16(a, wb, acc[ot], 0, 0, 0);
        }
        if (ch < 7) {
            xs[buf ^ 1][na][ca] = bf16_rne(la);
            xs[buf ^ 1][nb2][cb] = bf16_rne(lb);
        }
        __syncthreads();
    }
    const int n = n0 + ws * 16 + quad * 4;
#pragma unroll
    for (int ot = 0; ot < 5; ++ot) {
        const int gro = oq * 5 + ot;
        if (gro < 4) {
            const int o = gro * 16 + l15;
#pragma unroll
            for (int r = 0; r < 4; ++r)
                qkT[((size_t)b * N_ + n + r) * C4_ + o] = bf16_rne(acc[ot][r]);
        } else {
            const int c = (gro - 4) * 16 + l15;
            const float bb = bv[c];
            ushort4 u;
            u.x = bf16_rne(acc[ot][0] + bb);
            u.y = bf16_rne(acc[ot][1] + bb);
            u.z = bf16_rne(acc[ot][2] + bb);
            u.w = bf16_rne(acc[ot][3] + bb);
            *reinterpret_cast<ushort4*>(&v[((size_t)b * C_ + c) * N_ + n]) = u;
        }
    }
}

// rowsuminv[b,n] = 1/sum_m exp(e[n,m]). 16 waves = 4 n-strips x 4 m-subtiles.
__global__ __launch_bounds__(1024, 4) void rowsum_kernel(
        const unsigned short* __restrict__ qkT, float* __restrict__ rowsuminv) {
    __shared__ unsigned short kt[2][64][68];
    __shared__ float red[4][4][16];
    int b, nt;
    swizzle(blockIdx.x, b, nt);
    const int n0 = nt * 64;
    const int tid = threadIdx.x;
    const int wave = tid >> 6, lane = tid & 63;
    const int ws = wave & 3, sg = wave >> 2;
    const int quad = lane >> 4, l15 = lane & 15;
    const unsigned short* qb = qkT + (size_t)b * N_ * C4_;
    const unsigned short* qrow = qb + (size_t)(n0 + ws * 16 + l15) * C4_;
    const bf16x8 a0 = *reinterpret_cast<const bf16x8*>(qrow + quad * 8);
    const bf16x8 a1 = *reinterpret_cast<const bf16x8*>(qrow + 32 + quad * 8);
    const int srow = tid >> 3, soff = tid & 7;
    if (tid < 512) {
        const bf16x8 sk = *reinterpret_cast<const bf16x8*>(qb + (size_t)srow * C4_ + soff * 8);
        *reinterpret_cast<bf16x8*>(&kt[0][srow][soff * 8]) = sk;
    }
    __syncthreads();
    float cs[4] = {};
    for (int mt = 0; mt < 64; ++mt) {
        const int buf = mt & 1;
        bf16x8 nk;
        if (mt < 63 && tid < 512)
            nk = *reinterpret_cast<const bf16x8*>(
                qb + (size_t)((mt + 1) * 64 + srow) * C4_ + soff * 8);
        const bf16x8 kb0 = *reinterpret_cast<const bf16x8*>(&kt[buf][sg * 16 + l15][quad * 8]);
        const bf16x8 kb1 = *reinterpret_cast<const bf16x8*>(&kt[buf][sg * 16 + l15][32 + quad * 8]);
        f32x4 z = {0.f, 0.f, 0.f, 0.f};
        z = __builtin_amdgcn_mfma_f32_16x16x32_bf16(a0, kb0, z, 0, 0, 0);
        const f32x4 e = __builtin_amdgcn_mfma_f32_16x16x32_bf16(a1, kb1, z, 0, 0, 0);
#pragma unroll
        for (int r = 0; r < 4; ++r) cs[r] += __expf(e[r]);
        if (mt < 63 && tid < 512)
            *reinterpret_cast<bf16x8*>(&kt[buf ^ 1][srow][soff * 8]) = nk;
        __syncthreads();
    }
#pragma unroll
    for (int r = 0; r < 4; ++r) {
#pragma unroll
        for (int k = 1; k <= 8; k <<= 1) cs[r] += __shfl_xor(cs[r], k, 64);
        if (l15 == 0) red[sg][ws][quad * 4 + r] = cs[r];
    }
    __syncthreads();
    if (tid < 64) {
        const int ws2 = tid >> 4, row = tid & 15;
        const float sum = red[0][ws2][row] + red[1][ws2][row] +
                          red[2][ws2][row] + red[3][ws2][row];
        rowsuminv[(size_t)b * N_ + n0 + ws2 * 16 + row] = 1.0f / sum;
    }
}

// colsuminv[b,m] = 1/(1e-9 + sum_n exp(e[n,m])*rowsuminv[n]).
__global__ __launch_bounds__(1024, 4) void colsum_kernel(
        const unsigned short* __restrict__ qkT, const float* __restrict__ rowsuminv,
        float* __restrict__ colsuminv) {
    __shared__ float rl[N_];
    __shared__ unsigned short qt[2][64][68];
    __shared__ float red[4][4][16];
    int b, mtile;
    swizzle(blockIdx.x, b, mtile);
    const int m0 = mtile * 64;
    const int tid = threadIdx.x;
    const int wave = tid >> 6, lane = tid & 63;
    const int mw = wave & 3, ng = wave >> 2;
    const int quad = lane >> 4, l15 = lane & 15;
    for (int i = tid; i < N_; i += 1024) rl[i] = rowsuminv[(size_t)b * N_ + i];
    const unsigned short* qb = qkT + (size_t)b * N_ * C4_;
    const unsigned short* krow = qb + (size_t)(m0 + mw * 16 + l15) * C4_;
    const bf16x8 kb0 = *reinterpret_cast<const bf16x8*>(krow + quad * 8);
    const bf16x8 kb1 = *reinterpret_cast<const bf16x8*>(krow + 32 + quad * 8);
    const int srow = tid >> 3, soff = tid & 7;
    if (tid < 512) {
        const bf16x8 sq = *reinterpret_cast<const bf16x8*>(qb + (size_t)srow * C4_ + soff * 8);
        *reinterpret_cast<bf16x8*>(&qt[0][srow][soff * 8]) = sq;
    }
    __syncthreads();
    float cs = 0.f;
    for (int ntl = 0; ntl < 64; ++ntl) {
        const int buf = ntl & 1;
        bf16x8 nq;
        if (ntl < 63 && tid < 512)
            nq = *reinterpret_cast<const bf16x8*>(
                qb + (size_t)((ntl + 1) * 64 + srow) * C4_ + soff * 8);
        const bf16x8 a0 = *reinterpret_cast<const bf16x8*>(&qt[buf][ng * 16 + l15][quad * 8]);
        const bf16x8 a1 = *reinterpret_cast<const bf16x8*>(&qt[buf][ng * 16 + l15][32 + quad * 8]);
        f32x4 z = {0.f, 0.f, 0.f, 0.f};
        z = __builtin_amdgcn_mfma_f32_16x16x32_bf16(a0, kb0, z, 0, 0, 0);
        const f32x4 e = __builtin_amdgcn_mfma_f32_16x16x32_bf16(a1, kb1, z, 0, 0, 0);
        const int nb = ntl * 64 + ng * 16 + quad * 4;
#pragma unroll
        for (int r = 0; r < 4; ++r) cs += __expf(e[r]) * rl[nb + r];
        if (ntl < 63 && tid < 512)
            *reinterpret_cast<bf16x8*>(&qt[buf ^ 1][srow][soff * 8]) = nq;
        __syncthreads();
    }
    cs += __shfl_xor(cs, 16, 64);
    cs += __shfl_xor(cs, 32, 64);
    if (quad == 0) red[ng][mw][l15] = cs;
    __syncthreads();
    if (tid < 64) {
        const int mw2 = tid >> 4, l = tid & 15;
        const float sum = red[0][mw2][l] + red[1][mw2][l] +
                          red[2][mw2][l] + red[3][mw2][l];
        colsuminv[(size_t)b * N_ + m0 + mw2 * 16 + l] = 1.0f / (1e-9f + sum);
    }
}

// Final: 16 waves = 4 n-strips x (2 m-halves x 2 ct-halves). One barrier per
// m-tile: per-wave energy (2x redundant over ct-halves) -> same-wave p round
// trip -> PV MFMA from staged v-tile. Then LDS merge, wt GEMM, BN+ReLU+res.
__global__ __launch_bounds__(1024, 4) void final_kernel(
        const float* __restrict__ x, const unsigned short* __restrict__ qkT,
        const unsigned short* __restrict__ v, const unsigned short* __restrict__ wtb,
        const float* __restrict__ rowsuminv, const float* __restrict__ colsuminv,
        const float* __restrict__ bt, const float* __restrict__ gamma,
        const float* __restrict__ beta, const float* __restrict__ rmean,
        const float* __restrict__ rvar, float* __restrict__ out) {
    __shared__ float ci[N_];                      // 16 KB
    __shared__ union {
        unsigned short vt[2][256][68];            // 68 KB
        unsigned short dsm[64][268];              // 33.5 KB
    } u;
    __shared__ union {
        struct {
            unsigned short kt[2][64][68];         // 17 KB
            unsigned short p[4][2][16][40];       // 10 KB
        } a;
        float red[4][2][4][16][16];               // 32 KB (merge, kt/p dead)
    } s2;
    int b, nt;
    swizzle(blockIdx.x, b, nt);
    const int n0 = nt * 64;
    const int tid = threadIdx.x;
    const int wave = tid >> 6, lane = tid & 63;
    const int ws = wave & 3, grp = wave >> 2;
    const int mh = grp & 1, ch = grp >> 1;
    const int quad = lane >> 4, l15 = lane & 15;
    for (int i = tid; i < N_; i += 1024) ci[i] = colsuminv[(size_t)b * N_ + i];
    const unsigned short* qb = qkT + (size_t)b * N_ * C4_;
    const unsigned short* qrow = qb + (size_t)(n0 + ws * 16 + l15) * C4_;
    const bf16x8 a0 = *reinterpret_cast<const bf16x8*>(qrow + quad * 8);
    const bf16x8 a1 = *reinterpret_cast<const bf16x8*>(qrow + 32 + quad * 8);
    float rli[4];
#pragma unroll
    for (int r = 0; r < 4; ++r)
        rli[r] = rowsuminv[(size_t)b * N_ + n0 + ws * 16 + quad * 4 + r];
    const unsigned short* vbg = v + (size_t)b * C_ * N_;
    const int vrow = tid >> 3, voff = tid & 7;
    {
        const bf16x8 sv0 = *reinterpret_cast<const bf16x8*>(vbg + (size_t)vrow * N_ + voff * 8);
        const bf16x8 sv1 = *reinterpret_cast<const bf16x8*>(vbg + (size_t)(vrow + 128) * N_ + voff * 8);
        *reinterpret_cast<bf16x8*>(&u.vt[0][vrow][voff * 8]) = sv0;
        *reinterpret_cast<bf16x8*>(&u.vt[0][vrow + 128][voff * 8]) = sv1;
        if (tid < 512) {
            const bf16x8 sk = *reinterpret_cast<const bf16x8*>(qb + (size_t)vrow * C4_ + voff * 8);
            *reinterpret_cast<bf16x8*>(&s2.a.kt[0][vrow][voff * 8]) = sk;
        }
    }
    __syncthreads();
    f32x4 acc[8];
#pragma unroll
    for (int j = 0; j < 8; ++j) acc[j] = (f32x4){0.f, 0.f, 0.f, 0.f};
    for (int mt = 0; mt < 64; ++mt) {
        const int buf = mt & 1;
        const int m0 = mt * 64;
        bf16x8 nv0, nv1, nk;
        if (mt < 63) {
            nv0 = *reinterpret_cast<const bf16x8*>(vbg + (size_t)vrow * N_ + m0 + 64 + voff * 8);
            nv1 = *reinterpret_cast<const bf16x8*>(vbg + (size_t)(vrow + 128) * N_ + m0 + 64 + voff * 8);
            if (tid < 512)
                nk = *reinterpret_cast<const bf16x8*>(
                    qb + (size_t)(m0 + 64 + vrow) * C4_ + voff * 8);
        }
        // energy for (ws strip) x (mh half: 2 subtiles of 16 m)
#pragma unroll
        for (int sub = 0; sub < 2; ++sub) {
            const int mrow = mh * 32 + sub * 16 + l15;
            const bf16x8 kb0 = *reinterpret_cast<const bf16x8*>(&s2.a.kt[buf][mrow][quad * 8]);
            const bf16x8 kb1 = *reinterpret_cast<const bf16x8*>(&s2.a.kt[buf][mrow][32 + quad * 8]);
            f32x4 z = {0.f, 0.f, 0.f, 0.f};
            z = __builtin_amdgcn_mfma_f32_16x16x32_bf16(a0, kb0, z, 0, 0, 0);
            const f32x4 e = __builtin_amdgcn_mfma_f32_16x16x32_bf16(a1, kb1, z, 0, 0, 0);
            const float civ = ci[m0 + mh * 32 + sub * 16 + l15];
#pragma unroll
            for (int r = 0; r < 4; ++r)
                s2.a.p[ws][mh][quad * 4 + r][sub * 16 + l15] =
                    bf16_rne(__expf(e[r]) * rli[r] * civ);
        }
        // same-wave LDS round trip (ch 0/1 write identical bytes; benign)
        const bf16x8 pa = *reinterpret_cast<const bf16x8*>(&s2.a.p[ws][mh][l15][quad * 8]);
#pragma unroll
        for (int j = 0; j < 8; ++j) {
            const int c0 = (ch * 8 + j) * 16;
            const bf16x8 vb = *reinterpret_cast<const bf16x8*>(
                &u.vt[buf][c0 + l15][mh * 32 + quad * 8]);
            acc[j] = __builtin_amdgcn_mfma_f32_16x16x32_bf16(pa, vb, acc[j], 0, 0, 0);
        }
        if (mt < 63) {
            *reinterpret_cast<bf16x8*>(&u.vt[buf ^ 1][vrow][voff * 8]) = nv0;
            *reinterpret_cast<bf16x8*>(&u.vt[buf ^ 1][vrow + 128][voff * 8]) = nv1;
            if (tid < 512)
                *reinterpret_cast<bf16x8*>(&s2.a.kt[buf ^ 1][vrow][voff * 8]) = nk;
        }
        __syncthreads();
    }
    // merge mh=1 into mh=0 (2 chunks of 4 ct to fit red)
#pragma unroll
    for (int chunk = 0; chunk < 2; ++chunk) {
        if (mh == 1) {
#pragma unroll
            for (int j2 = 0; j2 < 4; ++j2) {
                const int j = chunk * 4 + j2;
#pragma unroll
                for (int r = 0; r < 4; ++r)
                    s2.red[ws][ch][j2][quad * 4 + r][l15] = acc[j][r];
            }
        }
        __syncthreads();
        if (mh == 0) {
#pragma unroll
            for (int j2 = 0; j2 < 4; ++j2) {
                const int j = chunk * 4 + j2;
#pragma unroll
                for (int r = 0; r < 4; ++r)
                    acc[j][r] += s2.red[ws][ch][j2][quad * 4 + r][l15];
            }
        }
        __syncthreads();
    }
    // dsm = x - x_r (bf16); mh=0 waves hold the merged acc
    if (mh == 0) {
#pragma unroll
        for (int j = 0; j < 8; ++j) {
            const int c = (ch * 8 + j) * 16 + l15;
            const float4 xv = *reinterpret_cast<const float4*>(
                &x[((size_t)b * C_ + c) * N_ + n0 + ws * 16 + quad * 4]);
            const float xvr[4] = {xv.x, xv.y, xv.z, xv.w};
#pragma unroll
            for (int r = 0; r < 4; ++r)
                u.dsm[ws * 16 + quad * 4 + r][c] = bf16_rne(xvr[r] - acc[j][r]);
        }
    }
    __syncthreads();
    // wt GEMM: 4 strips x 4 o-quarters
    bf16x8 da[8];
#pragma unroll
    for (int k = 0; k < 8; ++k)
        da[k] = *reinterpret_cast<const bf16x8*>(&u.dsm[ws * 16 + l15][k * 32 + quad * 8]);
    f32x4 tacc[4];
#pragma unroll
    for (int j = 0; j < 4; ++j) tacc[j] = (f32x4){0.f, 0.f, 0.f, 0.f};
#pragma unroll
    for (int j = 0; j < 4; ++j) {
        const int ot = grp * 4 + j;
#pragma unroll
        for (int k = 0; k < 8; ++k) {
            const bf16x8 wb = *reinterpret_cast<const bf16x8*>(
                wtb + (size_t)(ot * 16 + l15) * C_ + k * 32 + quad * 8);
            tacc[j] = __builtin_amdgcn_mfma_f32_16x16x32_bf16(da[k], wb, tacc[j], 0, 0, 0);
        }
    }
#pragma unroll
    for (int j = 0; j < 4; ++j) {
        const int o = (grp * 4 + j) * 16 + l15;
        const float g = gamma[o] * rsqrtf(rvar[o] + 1e-5f);
        const float mn = rmean[o], bbet = beta[o], bo = bt[o];
        const size_t oi = ((size_t)b * C_ + o) * N_ + n0 + ws * 16 + quad * 4;
        const float4 xo = *reinterpret_cast<const float4*>(&x[oi]);
        float4 res;
        res.x = xo.x + fmaxf((tacc[j][0] + bo - mn) * g + bbet, 0.f);
        res.y = xo.y + fmaxf((tacc[j][1] + bo - mn) * g + bbet, 0.f);
        res.z = xo.z + fmaxf((tacc[j][2] + bo - mn) * g + bbet, 0.f);
        res.w = xo.w + fmaxf((tacc[j][3] + bo - mn) * g + bbet, 0.f);
        *reinterpret_cast<float4*>(&out[oi]) = res;
    }
}

}  // namespace

extern "C" void kernel_launch(void* const* d_in, const int* in_sizes, int n_in,
                              void* d_out, int out_size, void* d_ws, size_t ws_size,
                              hipStream_t stream) {
    const float* x = (const float*)d_in[0];
    const float* wq = (const float*)d_in[1];
    const float* wv = (const float*)d_in[2];
    const float* bv = (const float*)d_in[3];
    const float* wt = (const float*)d_in[4];
    const float* bt = (const float*)d_in[5];
    const float* gamma = (const float*)d_in[6];
    const float* beta = (const float*)d_in[7];
    const float* rmean = (const float*)d_in[8];
    const float* rvar = (const float*)d_in[9];
    float* out = (float*)d_out;

    char* base = (char*)d_ws;
    unsigned short* qkT = (unsigned short*)base;                        // 2 MB
    unsigned short* vw = (unsigned short*)(base + (2u << 20));          // 8 MB
    unsigned short* wtb = (unsigned short*)(base + (10u << 20));        // 128 KB
    unsigned short* wcomb = (unsigned short*)(base + (10u << 20) + (128u << 10));
    float* rowsuminv = (float*)(base + (10u << 20) + (288u << 10));     // 64 KB
    float* colsuminv = (float*)(base + (10u << 20) + (352u << 10));     // 64 KB

    cvt_kernel<<<dim3(144), dim3(256), 0, stream>>>(wq, wv, wt, wcomb, wtb);
    proj_kernel<<<dim3(256), dim3(1024), 0, stream>>>(x, wcomb, bv, qkT, vw);
    rowsum_kernel<<<dim3(256), dim3(1024), 0, stream>>>(qkT, rowsuminv);
    colsum_kernel<<<dim3(256), dim3(1024), 0, stream>>>(qkT, rowsuminv, colsuminv);
    final_kernel<<<dim3(256), dim3(1024), 0, stream>>>(
        x, qkT, vw, wtb, rowsuminv, colsuminv, bt, gamma, beta, rmean, rvar, out);
}